// Round 10
// baseline (241.800 us; speedup 1.0000x reference)
//
#include <hip/hip_runtime.h>

#define NITER 10

// ---------------- helpers ----------------

__device__ __forceinline__ uint32_t aload(const uint32_t* p) {
  return __hip_atomic_load(p, __ATOMIC_RELAXED, __HIP_MEMORY_SCOPE_AGENT);
}
__device__ __forceinline__ void astore(uint32_t* p, uint32_t v) {
  __hip_atomic_store(p, v, __ATOMIC_RELAXED, __HIP_MEMORY_SCOPE_AGENT);
}
__device__ __forceinline__ float bf2f_lo(uint32_t v) { return __uint_as_float(v << 16); }
__device__ __forceinline__ float bf2f_hi(uint32_t v) { return __uint_as_float(v & 0xFFFF0000u); }
__device__ __forceinline__ uint32_t f2bf_bits(float f) {  // RNE, top 16 bits
  uint32_t b = __float_as_uint(f);
  b += 0x7FFFu + ((b >> 16) & 1u);
  return b >> 16;
}
__device__ __forceinline__ uint32_t pack_bf16x2(float lo, float hi) {
  return f2bf_bits(lo) | (f2bf_bits(hi) << 16);
}

// ---------------- setup kernel 1: partial histograms (8 blocks) ----------------

__global__ __launch_bounds__(1024) void hist_kernel(
    const int* __restrict__ src, const int* __restrict__ tgt,
    int* __restrict__ partS, int* __restrict__ partT, int E, int N) {
  __shared__ int h[4096];
  for (int i = threadIdx.x; i < 2 * N; i += 1024) h[i] = 0;
  __syncthreads();
  const int chunk = E / 8;
  const int base = blockIdx.x * chunk;
  const int cnt = (blockIdx.x == 7) ? (E - 7 * chunk) : chunk;
  for (int k = threadIdx.x; k < cnt; k += 1024) {
    int e = base + k;
    atomicAdd(&h[src[e]], 1);
    atomicAdd(&h[N + tgt[e]], 1);
  }
  __syncthreads();
  for (int i = threadIdx.x; i < N; i += 1024) {
    partS[blockIdx.x * 2048 + i] = h[i];
    partT[blockIdx.x * 2048 + i] = h[N + i];
  }
}

// ---------------- setup kernel 2: EXACT exclusive scan (+ zero barrier state) ----------
// blockIdx.x 0 -> S (also zeros bar), 1 -> T ; 256 threads x 8 = 2048 >= N+1

__global__ void scan_kernel(const int* __restrict__ partS, const int* __restrict__ partT,
                            int* __restrict__ offS, int* __restrict__ offT,
                            int* __restrict__ curS, int* __restrict__ curT,
                            uint32_t* __restrict__ bar, int N) {
  if (blockIdx.x == 0) {
    for (int i = threadIdx.x; i < 512; i += 256) bar[i] = 0u;  // leaves+root+gen
  }
  const int* part = (blockIdx.x == 0) ? partS : partT;
  int* off = (blockIdx.x == 0) ? offS : offT;
  int* cur = (blockIdx.x == 0) ? curS : curT;
  __shared__ int tsum[256];
  int tid = threadIdx.x;
  int base = tid * 8;
  int v[8];
  int s = 0;
#pragma unroll
  for (int i = 0; i < 8; ++i) {
    int idx = base + i;
    int c = 0;
    if (idx < N) {
#pragma unroll
      for (int k = 0; k < 8; ++k) c += part[k * 2048 + idx];
    }
    v[i] = s;
    s += c;
  }
  tsum[tid] = s;
  __syncthreads();
  for (int d = 1; d < 256; d <<= 1) {
    int t = (tid >= d) ? tsum[tid - d] : 0;
    __syncthreads();
    tsum[tid] += t;
    __syncthreads();
  }
  int tbase = tsum[tid] - s;
#pragma unroll
  for (int i = 0; i < 8; ++i) {
    int idx = base + i;
    if (idx < N) {
      int o = tbase + v[i];
      off[idx] = o;
      cur[idx] = o;
    } else if (idx == N) {
      off[idx] = tbase + v[i];  // total = E
    }
  }
}

// ---------------- setup kernel 3: scatter edges into CSR (no padding) ----------------

__global__ void scatter_kernel(const int* __restrict__ src, const int* __restrict__ tgt,
                               const float* __restrict__ w,
                               int* __restrict__ curS, int* __restrict__ curT,
                               uint32_t* __restrict__ edgeS, uint32_t* __restrict__ edgeT, int E) {
  int e = blockIdx.x * blockDim.x + threadIdx.x;
  if (e < E) {
    int s = src[e], t = tgt[e];
    uint32_t wb = __float_as_uint(w[e]);
    wb = (wb + 0x7FFFu + ((wb >> 16) & 1u)) & 0xFFFF0000u;  // bf16 bits, high half
    int p = atomicAdd(&curS[s], 1);
    edgeS[p] = (uint32_t)t | wb;  // mu pass: grouped by src, gathers fx[tgt]
    int q = atomicAdd(&curT[t], 1);
    edgeT[q] = (uint32_t)s | wb;  // agg pass: grouped by tgt, gathers err[src]
  }
}

// ---------------- main cooperative kernel ----------------
// WPN waves per node (edge list split by true degree into WPN slices, each
// zero-padded to a multiple of 8 inside LDS). Primary wave (sub==0) owns node
// state and publishes. Tree barrier (proven round 4/8): sc1 write-through
// stores + vmcnt(0) drain before arrival; message reads are agent (LLC) loads;
// no cache invalidation anywhere.

__device__ __forceinline__ void gbar(uint32_t* bar, uint32_t target) {
  asm volatile("s_waitcnt vmcnt(0)" ::: "memory");
  __syncthreads();
  if (threadIdx.x == 0) {
    const int nb = gridDim.x;
    const int li = blockIdx.x & 15;
    uint32_t* leaf = bar + li * 16;
    uint32_t* root = bar + 256;
    uint32_t* gen = bar + 272;
    const int q = nb >> 4, r = nb & 15;
    const uint32_t leafsz = (uint32_t)(li < r ? q + 1 : q);
    uint32_t lo = __hip_atomic_fetch_add(leaf, 1u, __ATOMIC_RELAXED, __HIP_MEMORY_SCOPE_AGENT);
    if (lo == leafsz - 1) {
      astore(leaf, 0u);
      asm volatile("s_waitcnt vmcnt(0)" ::: "memory");
      uint32_t ro = __hip_atomic_fetch_add(root, 1u, __ATOMIC_RELAXED, __HIP_MEMORY_SCOPE_AGENT);
      if (ro == 15u) {
        astore(root, 0u);
        asm volatile("s_waitcnt vmcnt(0)" ::: "memory");
        astore(gen, target);
      }
    }
    while (aload(gen) < target) __builtin_amdgcn_s_sleep(2);
  }
  __syncthreads();
  asm volatile("" ::: "memory");
}

// slice gather from LDS (len multiple of 8; pad entries idx=0,w=0)
__device__ __forceinline__ void gq_lds(const uint32_t* __restrict__ se, int len,
                                       const uint32_t* buf, int lane, float& o0, float& o1) {
  float a0[8], a1[8];
#pragma unroll
  for (int j = 0; j < 8; ++j) { a0[j] = 0.f; a1[j] = 0.f; }
  for (int p = 0; p < len; p += 8) {
    uint32_t e[8];
#pragma unroll
    for (int j = 0; j < 8; ++j) e[j] = se[p + j];
    uint32_t v[8];
#pragma unroll
    for (int j = 0; j < 8; ++j) v[j] = aload(&buf[((e[j] & 0xFFFFu) << 6) + lane]);
#pragma unroll
    for (int j = 0; j < 8; ++j) {
      float wj = __uint_as_float(e[j] & 0xFFFF0000u);
      a0[j] = fmaf(wj, bf2f_lo(v[j]), a0[j]);
      a1[j] = fmaf(wj, bf2f_hi(v[j]), a1[j]);
    }
  }
  o0 = ((a0[0] + a0[1]) + (a0[2] + a0[3])) + ((a0[4] + a0[5]) + (a0[6] + a0[7]));
  o1 = ((a1[0] + a1[1]) + (a1[2] + a1[3])) + ((a1[4] + a1[5]) + (a1[6] + a1[7]));
}

// fallback: straight from global CSR, guarded (only if slice > CAP; rare)
__device__ __forceinline__ void gq_glb(const uint32_t* __restrict__ ed, int len,
                                       const uint32_t* buf, int lane, float& o0, float& o1) {
  float a0[8], a1[8];
#pragma unroll
  for (int j = 0; j < 8; ++j) { a0[j] = 0.f; a1[j] = 0.f; }
  for (int p = 0; p < len; p += 8) {
    uint32_t e[8], v[8];
#pragma unroll
    for (int j = 0; j < 8; ++j) {
      bool ok = (p + j) < len;
      e[j] = ok ? ed[p + j] : 0u;
      v[j] = ok ? aload(&buf[((e[j] & 0xFFFFu) << 6) + lane]) : 0u;
    }
#pragma unroll
    for (int j = 0; j < 8; ++j) {
      float wj = __uint_as_float(e[j] & 0xFFFF0000u);
      a0[j] = fmaf(wj, bf2f_lo(v[j]), a0[j]);
      a1[j] = fmaf(wj, bf2f_hi(v[j]), a1[j]);
    }
  }
  o0 = ((a0[0] + a0[1]) + (a0[2] + a0[3])) + ((a0[4] + a0[5]) + (a0[6] + a0[7]));
  o1 = ((a1[0] + a1[1]) + (a1[2] + a1[3])) + ((a1[4] + a1[5]) + (a1[6] + a1[7]));
}

template <int WPN, int CAP>
__global__ __launch_bounds__(1024, 8) void pc_main(
    const float* __restrict__ x, float* __restrict__ out,
    const int* __restrict__ offS, const uint32_t* __restrict__ edS,
    const int* __restrict__ offT, const uint32_t* __restrict__ edT,
    uint32_t* fx32, uint32_t* err32, const float* __restrict__ mask,
    uint32_t* bar, int N) {
  constexpr int NPB = 16 / WPN;  // nodes per block
  __shared__ uint32_t sE[2][16][CAP];
  __shared__ float2 psum[16][64];

  const int tid = threadIdx.x;
  const int wid = tid >> 6;
  const int lane = tid & 63;
  const int sub = wid & (WPN - 1);
  int n = blockIdx.x * NPB + (wid / WPN);
  if (n >= N) n = N - 1;  // safety clamp (duplicate work is benign/deterministic)
  const int i = (n << 6) + lane;

  const int s0 = offS[n], degS = offS[n + 1] - s0;
  const int t0 = offT[n], degT = offT[n + 1] - t0;
  const int aS = s0 + (degS * sub) / WPN, qlS = (s0 + (degS * (sub + 1)) / WPN) - aS;
  const int aT = t0 + (degT * sub) / WPN, qlT = (t0 + (degT * (sub + 1)) / WPN) - aT;
  const int qpS = (qlS + 7) & ~7, qpT = (qlT + 7) & ~7;
  const bool fS = (qpS <= CAP), fT = (qpT <= CAP);
  if (fS)
    for (int k = lane; k < qpS; k += 64) sE[0][wid][k] = (k < qlS) ? edS[aS + k] : 0u;
  if (fT)
    for (int k = lane; k < qpT; k += 64) sE[1][wid][k] = (k < qlT) ? edT[aT + k] : 0u;

  // primary owns node state; lane l owns batch (2l, 2l+1)
  float m = 0.f, x0 = 0.f, x1 = 0.f, fx0 = 0.f, fx1 = 0.f, e0 = 0.f, e1 = 0.f;
  if (sub == 0) {
    m = mask[n];
    x0 = x[(2 * lane) * N + n];
    x1 = x[(2 * lane + 1) * N + n];
    fx0 = tanhf(x0);
    fx1 = tanhf(x1);
    astore(&fx32[i], pack_bf16x2(fx0, fx1));
  }
  uint32_t gen = 0;
  gbar(bar, ++gen);

  for (int it = 0; it < NITER; ++it) {
    // phase 1: mu partial-gather over fx; combine; publish err
    float p0, p1;
    if (fS) gq_lds(&sE[0][wid][0], qpS, fx32, lane, p0, p1);
    else    gq_glb(edS + aS, qlS, fx32, lane, p0, p1);
    if (sub) psum[wid][lane] = make_float2(p0, p1);
    __syncthreads();
    if (sub == 0) {
      float mu0 = p0, mu1 = p1;
#pragma unroll
      for (int j = 1; j < WPN; ++j) {
        float2 q = psum[wid + j][lane];
        mu0 += q.x;
        mu1 += q.y;
      }
      e0 = (x0 - mu0) * m;
      e1 = (x1 - mu1) * m;
      astore(&err32[i], pack_bf16x2(e0, e1));
    }
    gbar(bar, ++gen);

    // phase 2: agg partial-gather over err; combine; update x; publish fx
    if (fT) gq_lds(&sE[1][wid][0], qpT, err32, lane, p0, p1);
    else    gq_glb(edT + aT, qlT, err32, lane, p0, p1);
    if (sub) psum[wid][lane] = make_float2(p0, p1);
    __syncthreads();
    if (sub == 0) {
      float ag0 = p0, ag1 = p1;
#pragma unroll
      for (int j = 1; j < WPN; ++j) {
        float2 q = psum[wid + j][lane];
        ag0 += q.x;
        ag1 += q.y;
      }
      const float dx0 = e0 - (1.f - fx0 * fx0) * ag0;
      const float dx1 = e1 - (1.f - fx1 * fx1) * ag1;
      x0 -= 0.5f * dx0 * m;
      x1 -= 0.5f * dx1 * m;
      fx0 = tanhf(x0);
      fx1 = tanhf(x1);
      if (it < NITER - 1) astore(&fx32[i], pack_bf16x2(fx0, fx1));
    }
    if (it < NITER - 1) gbar(bar, ++gen);
  }

  if (sub == 0) {
    out[(2 * lane) * N + n] = x0;
    out[(2 * lane + 1) * N + n] = x1;
  }
}

// ---------------- host ----------------

extern "C" void kernel_launch(void* const* d_in, const int* in_sizes, int n_in,
                              void* d_out, int out_size, void* d_ws, size_t ws_size,
                              hipStream_t stream) {
  const float* x = (const float*)d_in[0];
  const int* ei = (const int*)d_in[1];
  const float* w = (const float*)d_in[2];
  const float* mask = (const float*)d_in[3];
  int E = in_sizes[2];  // 131072
  int N = in_sizes[3];  // 2000
  const int* src = ei;
  const int* tgt = ei + E;
  float* out = (float*)d_out;

  size_t off = 0;
  auto alloc = [&](size_t bytes) -> void* {
    off = (off + 255) & ~(size_t)255;
    void* p = (char*)d_ws + off;
    off += bytes;
    return p;
  };
  uint32_t* edgeS = (uint32_t*)alloc((size_t)E * 4);
  uint32_t* edgeT = (uint32_t*)alloc((size_t)E * 4);
  int* partS = (int*)alloc(8 * 2048 * 4);
  int* partT = (int*)alloc(8 * 2048 * 4);
  int* offS = (int*)alloc(2048 * 4);
  int* offT = (int*)alloc(2048 * 4);
  int* curS = (int*)alloc(2048 * 4);
  int* curT = (int*)alloc(2048 * 4);
  uint32_t* fx32 = (uint32_t*)alloc((size_t)N * 64 * 4);
  uint32_t* err32 = (uint32_t*)alloc((size_t)N * 64 * 4);
  uint32_t* bar = (uint32_t*)alloc(512 * 4);

  hist_kernel<<<8, 1024, 0, stream>>>(src, tgt, partS, partT, E, N);
  scan_kernel<<<2, 256, 0, stream>>>(partS, partT, offS, offT, curS, curT, bar, N);
  scatter_kernel<<<(E + 255) / 256, 256, 0, stream>>>(src, tgt, w, curS, curT, edgeS, edgeT, E);

  void* args[] = {(void*)&x,    (void*)&out,   (void*)&offS, (void*)&edgeS,
                  (void*)&offT, (void*)&edgeT, (void*)&fx32, (void*)&err32,
                  (void*)&mask, (void*)&bar,   (void*)&N};

  // Pick geometry by queried occupancy so the coop launch can never fail
  // (round 9: 500-block launch was rejected -> kernel never ran).
  int occ4 = 0;
  (void)hipOccupancyMaxActiveBlocksPerMultiprocessor(
      &occ4, (const void*)&pc_main<4, 48>, 1024, 0);
  if (occ4 >= 2) {
    const int nblk = (N + 3) / 4;  // 500: 4 waves/node, 32 waves/CU
    hipLaunchCooperativeKernel((const void*)&pc_main<4, 48>, dim3(nblk), dim3(1024), args, 0,
                               stream);
  } else {
    const int nblk = (N + 7) / 8;  // 250: 2 waves/node (round-8 proven geometry)
    hipLaunchCooperativeKernel((const void*)&pc_main<2, 96>, dim3(nblk), dim3(1024), args, 0,
                               stream);
  }
}